// Round 10
// baseline (600.332 us; speedup 1.0000x reference)
//
#include <hip/hip_runtime.h>

#define N_NODES 100000
#define N_EDGES 1600000
#define D 64
#define N_GRAPHS 64
#define D_LIN 256
#define D_OUT 128
#define BN_EPS 1e-5f
#define NBUCK 782  // ceil(100000/128), bucket = dst>>7 (128-node ranges)
#define BIN_CH 16384
#define ESTAGE 768  // staged edges per 16-row tile (avg 256, mean+32 sigma)

typedef unsigned short ushort;
typedef unsigned int uint;
typedef float floatx4 __attribute__((ext_vector_type(4)));
typedef uint uintx2 __attribute__((ext_vector_type(2)));

__device__ __forceinline__ float4 ld4(const float* p) { return *(const float4*)p; }

__device__ __forceinline__ uint f2bf(float f) {
  uint u = __float_as_uint(f);
  return (u + 0x7FFFu + ((u >> 16) & 1u)) >> 16;  // RNE
}

// ---------------- x -> bf16 prepass ----------------
__global__ __launch_bounds__(256) void k_cvt(const float* __restrict__ in,
                                             ushort* __restrict__ out, int n8) {
  int i = blockIdx.x * 256 + threadIdx.x;
  if (i < n8) {
    float4 a = ((const float4*)in)[2 * i];
    float4 b = ((const float4*)in)[2 * i + 1];
    uint4 o;
    o.x = f2bf(a.x) | (f2bf(a.y) << 16);
    o.y = f2bf(a.z) | (f2bf(a.w) << 16);
    o.z = f2bf(b.x) | (f2bf(b.y) << 16);
    o.w = f2bf(b.z) | (f2bf(b.w) << 16);
    ((uint4*)out)[i] = o;
  }
}

// ---------------- CSR build: bucketed counting sort ----------------
__global__ __launch_bounds__(256) void k_hist(const int* __restrict__ dstA,
                                              int* __restrict__ bcnt) {
  __shared__ int lh[NBUCK];
  for (int i = threadIdx.x; i < NBUCK; i += 256) lh[i] = 0;
  __syncthreads();
  int i = blockIdx.x * 256 + threadIdx.x;
  const int stride = gridDim.x * 256;
  for (; i < N_EDGES; i += stride) atomicAdd(&lh[dstA[i] >> 7], 1);
  __syncthreads();
  for (int i = threadIdx.x; i < NBUCK; i += 256)
    if (lh[i]) atomicAdd(&bcnt[i], lh[i]);
}

__global__ __launch_bounds__(1024) void k_bscan(const int* __restrict__ bcnt,
                                                int* __restrict__ boff,
                                                int* __restrict__ bcur) {
  __shared__ int s[1024];
  int t = threadIdx.x;
  int v = (t < NBUCK) ? bcnt[t] : 0;
  s[t] = v;
  __syncthreads();
  for (int off = 1; off < 1024; off <<= 1) {
    int u = (t >= off) ? s[t - off] : 0;
    __syncthreads();
    s[t] += u;
    __syncthreads();
  }
  if (t < NBUCK) {
    boff[t] = s[t] - v;  // exclusive
    bcur[t] = s[t] - v;
  }
}

__global__ __launch_bounds__(256) void k_bin(const int* __restrict__ srcA,
                                             const int* __restrict__ dstA,
                                             int* __restrict__ bcur,
                                             uint2* __restrict__ pairs) {
  __shared__ int lh[NBUCK];
  __shared__ int lbase[NBUCK];
  const int tid = threadIdx.x;
  for (int i = tid; i < NBUCK; i += 256) lh[i] = 0;
  __syncthreads();
  const int e0 = blockIdx.x * BIN_CH;
  const int e1 = min(e0 + BIN_CH, N_EDGES);
  for (int i = e0 + tid; i < e1; i += 256) atomicAdd(&lh[dstA[i] >> 7], 1);
  __syncthreads();
  for (int b = tid; b < NBUCK; b += 256) {
    int c = lh[b];
    if (c) lbase[b] = atomicAdd(&bcur[b], c);
  }
  __syncthreads();
  for (int b = tid; b < NBUCK; b += 256) lh[b] = 0;
  __syncthreads();
  for (int i = e0 + tid; i < e1; i += 256) {
    int d = dstA[i];
    int b = d >> 7;
    int p = lbase[b] + atomicAdd(&lh[b], 1);
    pairs[p] = make_uint2((uint)srcA[i], (uint)d);
  }
}

__global__ __launch_bounds__(256) void k_bucket(const uint2* __restrict__ pairs,
                                                const int* __restrict__ boff,
                                                const int* __restrict__ bcnt,
                                                int* __restrict__ rowptr,
                                                int* __restrict__ colidx) {
  __shared__ int ldeg[128], lsc[128], lcur[128];
  __shared__ int stage[4096];
  const int tid = threadIdx.x;
  const int b = blockIdx.x;
  const int node0 = b << 7;
  const int base = boff[b], cnt = bcnt[b];
  if (tid < 128) ldeg[tid] = 0;
  __syncthreads();
  for (int i = tid; i < cnt; i += 256) atomicAdd(&ldeg[pairs[base + i].y & 127], 1);
  __syncthreads();
  if (tid < 128) lsc[tid] = ldeg[tid];
  __syncthreads();
  for (int off = 1; off < 128; off <<= 1) {
    int u = (tid < 128 && tid >= off) ? lsc[tid - off] : 0;
    __syncthreads();
    if (tid < 128) lsc[tid] += u;
    __syncthreads();
  }
  if (tid < 128) {
    int excl = lsc[tid] - ldeg[tid];
    lcur[tid] = excl;
    int node = node0 + tid;
    if (node < N_NODES) rowptr[node] = base + excl;
  }
  if (b == NBUCK - 1 && tid == 0) rowptr[N_NODES] = N_EDGES;
  __syncthreads();
  if (cnt <= 4096) {
    for (int i = tid; i < cnt; i += 256) {
      uint2 pr = pairs[base + i];
      int p = atomicAdd(&lcur[pr.y & 127], 1);
      stage[p] = (int)pr.x;
    }
    __syncthreads();
    for (int i = tid; i < cnt; i += 256) colidx[base + i] = stage[i];
  } else {  // safety fallback, statistically never taken
    for (int i = tid; i < cnt; i += 256) {
      uint2 pr = pairs[base + i];
      int p = atomicAdd(&lcur[pr.y & 127], 1);
      colidx[base + p] = (int)pr.x;
    }
  }
}

// ---------------- fused GIN conv layer ----------------
// SINGLE-WAVE blocks: 64 threads, 16-row tile, 6250 blocks. No inter-wave
// convoying; up to 16 workgroups/CU. Group g = lane>>3 owns one row, lane
// holds 8 private features (no cross-lane reduce). Edge indices staged in
// LDS. Rows are DEGREE-RANKED and batched by rank (ranks 0-7, then 8-15)
// so the 8 groups of a batch have near-equal trip counts -> minimal
// exec-mask waste. Unroll-16 keeps ~16 gather instrs in flight per wave.
template <int APPLY_BN, int EMIT_STATS, int OUT_BF>
__global__ __launch_bounds__(64, 4) void k_conv(
    const ushort* __restrict__ h_in, const float* __restrict__ ss,
    const int* __restrict__ rowptr, const int* __restrict__ colidx,
    const float* __restrict__ w1, const float* __restrict__ b1,
    const float* __restrict__ w2, const float* __restrict__ b2,
    float* __restrict__ h_out_f, ushort* __restrict__ h_out_bf,
    float* __restrict__ stats) {
  __shared__ float sT[16][68];
  __shared__ float sSum[64], sSq[64];
  __shared__ int sEdge[ESTAGE];
  __shared__ int sRp[17];
  __shared__ int sDeg[16], sOrd[16];

  const int tid = threadIdx.x;
  const int g = tid >> 3;          // row slot within wave (0..7)
  const int fl = (tid & 7) << 3;   // first of this lane's 8 features
  const int row0 = blockIdx.x * 16;

  if (EMIT_STATS) { sSum[tid] = 0.f; sSq[tid] = 0.f; }
  if (tid < 17) sRp[tid] = rowptr[row0 + tid];
  __syncthreads();
  if (tid < 16) sDeg[tid] = sRp[tid + 1] - sRp[tid];
  __syncthreads();
  if (tid < 16) {  // degree rank (stable)
    const int d = sDeg[tid];
    int rk = 0;
#pragma unroll
    for (int j = 0; j < 16; ++j) {
      int dj = sDeg[j];
      rk += (dj < d) || (dj == d && j < tid);
    }
    sOrd[rk] = tid;
  }

  const int ebase = sRp[0];
  const int ecnt = sRp[16] - ebase;
  const int estage = min(ecnt, ESTAGE);
  for (int i = tid; i < estage; i += 64)
    sEdge[i] = __builtin_nontemporal_load(colidx + ebase + i);
  __syncthreads();

  float sc[8], sh[8];
  if (APPLY_BN) {
    float4 a = ld4(&ss[fl]), b = ld4(&ss[fl + 4]);
    float4 c = ld4(&ss[64 + fl]), d = ld4(&ss[64 + fl + 4]);
    sc[0] = a.x; sc[1] = a.y; sc[2] = a.z; sc[3] = a.w;
    sc[4] = b.x; sc[5] = b.y; sc[6] = b.z; sc[7] = b.w;
    sh[0] = c.x; sh[1] = c.y; sh[2] = c.z; sh[3] = c.w;
    sh[4] = d.x; sh[5] = d.y; sh[6] = d.z; sh[7] = d.w;
  }

#define ACC8(u)                                                        \
  {                                                                    \
    float f0 = __uint_as_float((u).x << 16);                           \
    float f1 = __uint_as_float((u).x & 0xffff0000u);                   \
    float f2 = __uint_as_float((u).y << 16);                           \
    float f3 = __uint_as_float((u).y & 0xffff0000u);                   \
    float f4 = __uint_as_float((u).z << 16);                           \
    float f5 = __uint_as_float((u).z & 0xffff0000u);                   \
    float f6 = __uint_as_float((u).w << 16);                           \
    float f7 = __uint_as_float((u).w & 0xffff0000u);                   \
    if (APPLY_BN) {                                                    \
      f0 = fmaxf(fmaf(f0, sc[0], sh[0]), 0.f);                         \
      f1 = fmaxf(fmaf(f1, sc[1], sh[1]), 0.f);                         \
      f2 = fmaxf(fmaf(f2, sc[2], sh[2]), 0.f);                         \
      f3 = fmaxf(fmaf(f3, sc[3], sh[3]), 0.f);                         \
      f4 = fmaxf(fmaf(f4, sc[4], sh[4]), 0.f);                         \
      f5 = fmaxf(fmaf(f5, sc[5], sh[5]), 0.f);                         \
      f6 = fmaxf(fmaf(f6, sc[6], sh[6]), 0.f);                         \
      f7 = fmaxf(fmaf(f7, sc[7], sh[7]), 0.f);                         \
    }                                                                  \
    acc[0] += f0; acc[1] += f1; acc[2] += f2; acc[3] += f3;            \
    acc[4] += f4; acc[5] += f5; acc[6] += f6; acc[7] += f7;            \
  }
#define GATHER(s) *(const uint4*)(h_in + ((size_t)(s) << 6) + fl)

  // ---- phase 1: gather (2 degree-ranked batches of 8 rows) ----
#pragma unroll
  for (int b = 0; b < 2; ++b) {
    const int r = sOrd[(b << 3) + g];
    const int row = row0 + r;
    float acc[8] = {0.f, 0.f, 0.f, 0.f, 0.f, 0.f, 0.f, 0.f};
    {  // self term
      uint4 u = GATHER(row);
      ACC8(u);
    }
    const int re0 = sRp[r] - ebase;
    const int re1g = sRp[r + 1] - ebase;
    const int re1 = min(re1g, estage);
    int e = re0;
    for (; e + 15 < re1; e += 16) {
      int s[16];
#pragma unroll
      for (int j = 0; j < 16; ++j) s[j] = sEdge[e + j];
      uint4 u[16];
#pragma unroll
      for (int j = 0; j < 16; ++j) u[j] = GATHER(s[j]);
#pragma unroll
      for (int j = 0; j < 16; ++j) ACC8(u[j]);
    }
    if (e < re1) {  // masked tail: clamped LDS reads, predicated acc
      const int em = re1 - 1;
      int s[16];
#pragma unroll
      for (int j = 0; j < 16; ++j) s[j] = sEdge[min(e + j, em)];
      uint4 u[16];
#pragma unroll
      for (int j = 0; j < 16; ++j) u[j] = GATHER(s[j]);
      ACC8(u[0]);
#pragma unroll
      for (int j = 1; j < 16; ++j)
        if (e + j < re1) ACC8(u[j]);
    }
    // overflow beyond staged range (statistically never taken)
    for (int eg2 = ebase + max(re0, estage); eg2 < ebase + re1g; ++eg2) {
      int s0 = colidx[eg2];
      uint4 u0 = GATHER(s0);
      ACC8(u0);
    }
    *(float4*)&sT[r][fl] = make_float4(acc[0], acc[1], acc[2], acc[3]);
    *(float4*)&sT[r][fl + 4] = make_float4(acc[4], acc[5], acc[6], acc[7]);
  }
#undef GATHER
#undef ACC8
  __syncthreads();

  const int tc = tid & 15, tr = tid >> 4;  // cols 4*tc.., rows 4*tr.. (tr 0..3)

  // ---- GEMM1: h1 = relu(t @ w1 + b1), regs, write back to sT ----
  float hreg[4][4];
  {
    float acc[4][4];
#pragma unroll
    for (int i = 0; i < 4; ++i)
#pragma unroll
      for (int j = 0; j < 4; ++j) acc[i][j] = 0.f;
#pragma unroll 8
    for (int k = 0; k < 64; ++k) {
      const float4 b = ld4(&w1[(k << 6) + (tc << 2)]);
#pragma unroll
      for (int i = 0; i < 4; ++i) {
        const float a = sT[(tr << 2) + i][k];
        acc[i][0] = fmaf(a, b.x, acc[i][0]);
        acc[i][1] = fmaf(a, b.y, acc[i][1]);
        acc[i][2] = fmaf(a, b.z, acc[i][2]);
        acc[i][3] = fmaf(a, b.w, acc[i][3]);
      }
    }
    const float4 bb = ld4(&b1[tc << 2]);
#pragma unroll
    for (int i = 0; i < 4; ++i) {
      hreg[i][0] = fmaxf(acc[i][0] + bb.x, 0.f);
      hreg[i][1] = fmaxf(acc[i][1] + bb.y, 0.f);
      hreg[i][2] = fmaxf(acc[i][2] + bb.z, 0.f);
      hreg[i][3] = fmaxf(acc[i][3] + bb.w, 0.f);
    }
  }
  __syncthreads();
#pragma unroll
  for (int i = 0; i < 4; ++i)
    *(float4*)&sT[(tr << 2) + i][tc << 2] = *(float4*)&hreg[i][0];
  __syncthreads();

  // ---- GEMM2: h2 = h1 @ w2 + b2 -> global (+ BN stats) ----
  {
    float acc[4][4];
#pragma unroll
    for (int i = 0; i < 4; ++i)
#pragma unroll
      for (int j = 0; j < 4; ++j) acc[i][j] = 0.f;
#pragma unroll 8
    for (int k = 0; k < 64; ++k) {
      const float4 b = ld4(&w2[(k << 6) + (tc << 2)]);
#pragma unroll
      for (int i = 0; i < 4; ++i) {
        const float a = sT[(tr << 2) + i][k];
        acc[i][0] = fmaf(a, b.x, acc[i][0]);
        acc[i][1] = fmaf(a, b.y, acc[i][1]);
        acc[i][2] = fmaf(a, b.z, acc[i][2]);
        acc[i][3] = fmaf(a, b.w, acc[i][3]);
      }
    }
    const float4 bb = ld4(&b2[tc << 2]);
    float p[4] = {0.f, 0.f, 0.f, 0.f}, q[4] = {0.f, 0.f, 0.f, 0.f};
#pragma unroll
    for (int i = 0; i < 4; ++i) {
      const int row = row0 + (tr << 2) + i;
      float4 o;
      o.x = acc[i][0] + bb.x;
      o.y = acc[i][1] + bb.y;
      o.z = acc[i][2] + bb.z;
      o.w = acc[i][3] + bb.w;
      if (OUT_BF) {
        uintx2 o2;
        o2.x = f2bf(o.x) | (f2bf(o.y) << 16);
        o2.y = f2bf(o.z) | (f2bf(o.w) << 16);
        __builtin_nontemporal_store(o2, (uintx2*)(h_out_bf + ((size_t)row << 6) + (tc << 2)));
      } else {
        floatx4 o4;
        o4.x = o.x; o4.y = o.y; o4.z = o.z; o4.w = o.w;
        __builtin_nontemporal_store(o4, (floatx4*)&h_out_f[row * 64 + (tc << 2)]);
      }
      if (EMIT_STATS) {
        p[0] += o.x; q[0] += o.x * o.x;
        p[1] += o.y; q[1] += o.y * o.y;
        p[2] += o.z; q[2] += o.z * o.z;
        p[3] += o.w; q[3] += o.w * o.w;
      }
    }
    if (EMIT_STATS) {
#pragma unroll
      for (int j = 0; j < 4; ++j) {
        atomicAdd(&sSum[(tc << 2) + j], p[j]);
        atomicAdd(&sSq[(tc << 2) + j], q[j]);
      }
      __syncthreads();
      atomicAdd(&stats[tid], sSum[tid]);
      atomicAdd(&stats[64 + tid], sSq[tid]);
    }
  }
}

__global__ void k_bnfin(const float* __restrict__ stats, const float* __restrict__ gamma,
                        const float* __restrict__ beta, float* __restrict__ ss) {
  int t = threadIdx.x;
  if (t < 64) {
    const float inv_n = 1.f / (float)N_NODES;
    float mean = stats[t] * inv_n;
    float var = stats[64 + t] * inv_n - mean * mean;
    float scale = gamma[t] * rsqrtf(var + BN_EPS);
    ss[t] = scale;
    ss[64 + t] = beta[t] - mean * scale;
  }
}

// ---------------- global add pool (batch sorted) ----------------
__global__ __launch_bounds__(256) void k_pool(const float* __restrict__ h,
                                              const int* __restrict__ batch,
                                              float* __restrict__ emb) {
  const int NW = 1024;  // total waves
  const int RPW = (N_NODES + NW - 1) / NW;
  int wid = (blockIdx.x * 256 + threadIdx.x) >> 6;
  int lane = threadIdx.x & 63;
  int r0 = wid * RPW;
  if (r0 >= N_NODES) return;
  int r1 = min(r0 + RPW, N_NODES);
  float acc = 0.f;
  int curg = batch[r0];
  for (int i = r0; i < r1; ++i) {
    int g = batch[i];
    if (g != curg) {
      atomicAdd(&emb[curg * 64 + lane], acc);
      acc = 0.f;
      curg = g;
    }
    acc += h[i * 64 + lane];
  }
  atomicAdd(&emb[curg * 64 + lane], acc);
}

// ---------------- final MLP ----------------
__global__ __launch_bounds__(256) void k_mlp(const float* __restrict__ emb,
                                             const float* __restrict__ w1,
                                             const float* __restrict__ b1,
                                             const float* __restrict__ w2,
                                             const float* __restrict__ b2,
                                             float* __restrict__ out) {
  __shared__ float sp[64];
  __shared__ float smid[256];
  int g = blockIdx.x, t = threadIdx.x;
  if (t < 64) sp[t] = emb[g * 64 + t];
  __syncthreads();
  float acc = b1[t];
#pragma unroll 8
  for (int k = 0; k < 64; ++k) acc = fmaf(sp[k], w1[k * 256 + t], acc);
  smid[t] = fmaxf(acc, 0.f);
  __syncthreads();
  if (t < 128) {
    float o = b2[t];
#pragma unroll 8
    for (int k = 0; k < 256; ++k) o = fmaf(smid[k], w2[k * 128 + t], o);
    out[g * 128 + t] = o;
  }
}

extern "C" void kernel_launch(void* const* d_in, const int* in_sizes, int n_in,
                              void* d_out, int out_size, void* d_ws, size_t ws_size,
                              hipStream_t stream) {
  const float* x = (const float*)d_in[0];
  const int* edge = (const int*)d_in[1];
  const int* batch = (const int*)d_in[2];
  const float* cw1[3] = {(const float*)d_in[3], (const float*)d_in[7], (const float*)d_in[11]};
  const float* cb1[3] = {(const float*)d_in[4], (const float*)d_in[8], (const float*)d_in[12]};
  const float* cw2[3] = {(const float*)d_in[5], (const float*)d_in[9], (const float*)d_in[13]};
  const float* cb2[3] = {(const float*)d_in[6], (const float*)d_in[10], (const float*)d_in[14]};
  const float* bng[2] = {(const float*)d_in[15], (const float*)d_in[17]};
  const float* bnb[2] = {(const float*)d_in[16], (const float*)d_in[18]};
  const float* mpw1 = (const float*)d_in[19];
  const float* mpb1 = (const float*)d_in[20];
  const float* mpw2 = (const float*)d_in[21];
  const float* mpb2 = (const float*)d_in[22];

  char* ws = (char*)d_ws;
  size_t off = 0;
  auto alloc = [&](size_t bytes) {
    void* p = ws + off;
    off = (off + bytes + 255) & ~(size_t)255;
    return p;
  };
  int* rowptr = (int*)alloc((N_NODES + 1) * sizeof(int));
  int* colidx = (int*)alloc(N_EDGES * sizeof(int));
  int* bcnt = (int*)alloc(NBUCK * sizeof(int));
  int* boff = (int*)alloc(NBUCK * sizeof(int));
  int* bcur = (int*)alloc(NBUCK * sizeof(int));
  // x_bf and hA_bf contiguous (12.8 MB each); after layer 1 both are dead and
  // the combined 25.6 MB is reused as the fp32 layer-2 output hF.
  ushort* x_bf = (ushort*)alloc((size_t)N_NODES * 64 * sizeof(ushort));
  ushort* hA_bf = (ushort*)alloc((size_t)N_NODES * 64 * sizeof(ushort));
  ushort* hB_bf = (ushort*)alloc((size_t)N_NODES * 64 * sizeof(ushort));
  float* stats = (float*)alloc(2 * 128 * sizeof(float));
  float* ssbuf = (float*)alloc(2 * 128 * sizeof(float));
  float* hF = (float*)x_bf;
  // pairs (12.8 MB) aliases hB_bf: pairs is dead before layer 1 writes hB_bf.
  uint2* pairs = (uint2*)hB_bf;

  float* outp = (float*)d_out;
  float* emb = outp + N_GRAPHS * D_OUT;  // output 1 lives right after output 0

  const int* srcA = edge;
  const int* dstA = edge + N_EDGES;

  hipMemsetAsync(bcnt, 0, NBUCK * sizeof(int), stream);
  hipMemsetAsync(stats, 0, 2 * 128 * sizeof(float), stream);
  hipMemsetAsync(emb, 0, N_GRAPHS * 64 * sizeof(float), stream);

  k_cvt<<<(N_NODES * 64 / 8 + 255) / 256, 256, 0, stream>>>(x, x_bf, N_NODES * 64 / 8);
  k_hist<<<256, 256, 0, stream>>>(dstA, bcnt);
  k_bscan<<<1, 1024, 0, stream>>>(bcnt, boff, bcur);
  k_bin<<<(N_EDGES + BIN_CH - 1) / BIN_CH, 256, 0, stream>>>(srcA, dstA, bcur, pairs);
  k_bucket<<<NBUCK, 256, 0, stream>>>(pairs, boff, bcnt, rowptr, colidx);

  const int GC = N_NODES / 16;  // 6250, exact
  // layer 0: input x_bf (no BN on input), emit stats0, bf16 out
  k_conv<0, 1, 1><<<GC, 64, 0, stream>>>(x_bf, nullptr, rowptr, colidx, cw1[0], cb1[0],
                                         cw2[0], cb2[0], nullptr, hA_bf, stats);
  k_bnfin<<<1, 64, 0, stream>>>(stats, bng[0], bnb[0], ssbuf);
  // layer 1: input hA_bf with BN0+relu on the fly, emit stats1, bf16 out
  k_conv<1, 1, 1><<<GC, 64, 0, stream>>>(hA_bf, ssbuf, rowptr, colidx, cw1[1], cb1[1],
                                         cw2[1], cb2[1], nullptr, hB_bf, stats + 128);
  k_bnfin<<<1, 64, 0, stream>>>(stats + 128, bng[1], bnb[1], ssbuf + 128);
  // layer 2: input hB_bf with BN1+relu, fp32 out for pooling
  k_conv<1, 0, 0><<<GC, 64, 0, stream>>>(hB_bf, ssbuf + 128, rowptr, colidx, cw1[2],
                                         cb1[2], cw2[2], cb2[2], hF, nullptr, nullptr);

  k_pool<<<256, 256, 0, stream>>>(hF, batch, emb);
  k_mlp<<<N_GRAPHS, 256, 0, stream>>>(emb, mpw1, mpb1, mpw2, mpb2, outp);
}

// Round 11
// 444.736 us; speedup vs baseline: 1.3499x; 1.3499x over previous
//
#include <hip/hip_runtime.h>

#define N_NODES 100000
#define N_EDGES 1600000
#define D 64
#define N_GRAPHS 64
#define D_LIN 256
#define D_OUT 128
#define BN_EPS 1e-5f
#define NBUCK 782  // ceil(100000/128), bucket = dst>>7 (128-node ranges)
#define BIN_CH 16384

typedef unsigned short ushort;
typedef unsigned int uint;
typedef float floatx4 __attribute__((ext_vector_type(4)));
typedef uint uintx2 __attribute__((ext_vector_type(2)));

__device__ __forceinline__ float4 ld4(const float* p) { return *(const float4*)p; }

__device__ __forceinline__ uint f2bf(float f) {
  uint u = __float_as_uint(f);
  return (u + 0x7FFFu + ((u >> 16) & 1u)) >> 16;  // RNE
}

// ---------------- x -> bf16 prepass ----------------
__global__ __launch_bounds__(256) void k_cvt(const float* __restrict__ in,
                                             ushort* __restrict__ out, int n8) {
  int i = blockIdx.x * 256 + threadIdx.x;
  if (i < n8) {
    float4 a = ((const float4*)in)[2 * i];
    float4 b = ((const float4*)in)[2 * i + 1];
    uint4 o;
    o.x = f2bf(a.x) | (f2bf(a.y) << 16);
    o.y = f2bf(a.z) | (f2bf(a.w) << 16);
    o.z = f2bf(b.x) | (f2bf(b.y) << 16);
    o.w = f2bf(b.z) | (f2bf(b.w) << 16);
    ((uint4*)out)[i] = o;
  }
}

// ---------------- CSR build: bucketed counting sort ----------------
__global__ __launch_bounds__(256) void k_hist(const int* __restrict__ dstA,
                                              int* __restrict__ bcnt) {
  __shared__ int lh[NBUCK];
  for (int i = threadIdx.x; i < NBUCK; i += 256) lh[i] = 0;
  __syncthreads();
  int i = blockIdx.x * 256 + threadIdx.x;
  const int stride = gridDim.x * 256;
  for (; i < N_EDGES; i += stride) atomicAdd(&lh[dstA[i] >> 7], 1);
  __syncthreads();
  for (int i = threadIdx.x; i < NBUCK; i += 256)
    if (lh[i]) atomicAdd(&bcnt[i], lh[i]);
}

__global__ __launch_bounds__(1024) void k_bscan(const int* __restrict__ bcnt,
                                                int* __restrict__ boff,
                                                int* __restrict__ bcur) {
  __shared__ int s[1024];
  int t = threadIdx.x;
  int v = (t < NBUCK) ? bcnt[t] : 0;
  s[t] = v;
  __syncthreads();
  for (int off = 1; off < 1024; off <<= 1) {
    int u = (t >= off) ? s[t - off] : 0;
    __syncthreads();
    s[t] += u;
    __syncthreads();
  }
  if (t < NBUCK) {
    boff[t] = s[t] - v;  // exclusive
    bcur[t] = s[t] - v;
  }
}

__global__ __launch_bounds__(256) void k_bin(const int* __restrict__ srcA,
                                             const int* __restrict__ dstA,
                                             int* __restrict__ bcur,
                                             uint2* __restrict__ pairs) {
  __shared__ int lh[NBUCK];
  __shared__ int lbase[NBUCK];
  const int tid = threadIdx.x;
  for (int i = tid; i < NBUCK; i += 256) lh[i] = 0;
  __syncthreads();
  const int e0 = blockIdx.x * BIN_CH;
  const int e1 = min(e0 + BIN_CH, N_EDGES);
  for (int i = e0 + tid; i < e1; i += 256) atomicAdd(&lh[dstA[i] >> 7], 1);
  __syncthreads();
  for (int b = tid; b < NBUCK; b += 256) {
    int c = lh[b];
    if (c) lbase[b] = atomicAdd(&bcur[b], c);
  }
  __syncthreads();
  for (int b = tid; b < NBUCK; b += 256) lh[b] = 0;
  __syncthreads();
  for (int i = e0 + tid; i < e1; i += 256) {
    int d = dstA[i];
    int b = d >> 7;
    int p = lbase[b] + atomicAdd(&lh[b], 1);
    pairs[p] = make_uint2((uint)srcA[i], (uint)d);
  }
}

__global__ __launch_bounds__(256) void k_bucket(const uint2* __restrict__ pairs,
                                                const int* __restrict__ boff,
                                                const int* __restrict__ bcnt,
                                                int* __restrict__ rowptr,
                                                int* __restrict__ colidx) {
  __shared__ int ldeg[128], lsc[128], lcur[128];
  __shared__ int stage[4096];
  const int tid = threadIdx.x;
  const int b = blockIdx.x;
  const int node0 = b << 7;
  const int base = boff[b], cnt = bcnt[b];
  if (tid < 128) ldeg[tid] = 0;
  __syncthreads();
  for (int i = tid; i < cnt; i += 256) atomicAdd(&ldeg[pairs[base + i].y & 127], 1);
  __syncthreads();
  if (tid < 128) lsc[tid] = ldeg[tid];
  __syncthreads();
  for (int off = 1; off < 128; off <<= 1) {
    int u = (tid < 128 && tid >= off) ? lsc[tid - off] : 0;
    __syncthreads();
    if (tid < 128) lsc[tid] += u;
    __syncthreads();
  }
  if (tid < 128) {
    int excl = lsc[tid] - ldeg[tid];
    lcur[tid] = excl;
    int node = node0 + tid;
    if (node < N_NODES) rowptr[node] = base + excl;
  }
  if (b == NBUCK - 1 && tid == 0) rowptr[N_NODES] = N_EDGES;
  __syncthreads();
  if (cnt <= 4096) {
    for (int i = tid; i < cnt; i += 256) {
      uint2 pr = pairs[base + i];
      int p = atomicAdd(&lcur[pr.y & 127], 1);
      stage[p] = (int)pr.x;
    }
    __syncthreads();
    for (int i = tid; i < cnt; i += 256) colidx[base + i] = stage[i];
  } else {  // safety fallback, statistically never taken
    for (int i = tid; i < cnt; i += 256) {
      uint2 pr = pairs[base + i];
      int p = atomicAdd(&lcur[pr.y & 127], 1);
      colidx[base + p] = (int)pr.x;
    }
  }
}

// ---------------- fused GIN conv layer ----------------
// Round-5 geometry (best measured): 32-row tile, 128 threads (2 waves),
// each wave gathers 16 rows in 2 batches of 8. Group g = lane>>3 owns one
// row; lane holds 8 private features -> no cross-lane reduce.
// NEW: unroll-8 gather burst with REGISTER PINNING (asm "+v") between the
// load burst and the accumulates -> compiler must keep all 8 uint4 loads
// in flight (progressive vmcnt drains) instead of collapsing the pipeline
// to depth ~2 to save VGPRs. launch_bounds(128,4) lifts the VGPR cap to
// 128 so the 8 live uint4 + acc fit without spills.
#define PIN4(u) asm volatile("" : "+v"((u).x), "+v"((u).y), "+v"((u).z), "+v"((u).w))
template <int APPLY_BN, int EMIT_STATS, int OUT_BF>
__global__ __launch_bounds__(128, 4) void k_conv(
    const ushort* __restrict__ h_in, const float* __restrict__ ss,
    const int* __restrict__ rowptr, const int* __restrict__ colidx,
    const float* __restrict__ w1, const float* __restrict__ b1,
    const float* __restrict__ w2, const float* __restrict__ b2,
    float* __restrict__ h_out_f, ushort* __restrict__ h_out_bf,
    float* __restrict__ stats) {
  __shared__ float sT[32][68];
  __shared__ float sSum[64], sSq[64];

  const int tid = threadIdx.x;
  const int wave = tid >> 6, lane = tid & 63;
  const int g = lane >> 3;         // row slot within wave (0..7)
  const int fl = (lane & 7) << 3;  // first of this lane's 8 features
  const int row0 = blockIdx.x * 32;

  if (EMIT_STATS && tid < 64) { sSum[tid] = 0.f; sSq[tid] = 0.f; }

  float sc[8], sh[8];
  if (APPLY_BN) {
    float4 a = ld4(&ss[fl]), b = ld4(&ss[fl + 4]);
    float4 c = ld4(&ss[64 + fl]), d = ld4(&ss[64 + fl + 4]);
    sc[0] = a.x; sc[1] = a.y; sc[2] = a.z; sc[3] = a.w;
    sc[4] = b.x; sc[5] = b.y; sc[6] = b.z; sc[7] = b.w;
    sh[0] = c.x; sh[1] = c.y; sh[2] = c.z; sh[3] = c.w;
    sh[4] = d.x; sh[5] = d.y; sh[6] = d.z; sh[7] = d.w;
  }

#define ACC8(u)                                                        \
  {                                                                    \
    float f0 = __uint_as_float((u).x << 16);                           \
    float f1 = __uint_as_float((u).x & 0xffff0000u);                   \
    float f2 = __uint_as_float((u).y << 16);                           \
    float f3 = __uint_as_float((u).y & 0xffff0000u);                   \
    float f4 = __uint_as_float((u).z << 16);                           \
    float f5 = __uint_as_float((u).z & 0xffff0000u);                   \
    float f6 = __uint_as_float((u).w << 16);                           \
    float f7 = __uint_as_float((u).w & 0xffff0000u);                   \
    if (APPLY_BN) {                                                    \
      f0 = fmaxf(fmaf(f0, sc[0], sh[0]), 0.f);                         \
      f1 = fmaxf(fmaf(f1, sc[1], sh[1]), 0.f);                         \
      f2 = fmaxf(fmaf(f2, sc[2], sh[2]), 0.f);                         \
      f3 = fmaxf(fmaf(f3, sc[3], sh[3]), 0.f);                         \
      f4 = fmaxf(fmaf(f4, sc[4], sh[4]), 0.f);                         \
      f5 = fmaxf(fmaf(f5, sc[5], sh[5]), 0.f);                         \
      f6 = fmaxf(fmaf(f6, sc[6], sh[6]), 0.f);                         \
      f7 = fmaxf(fmaf(f7, sc[7], sh[7]), 0.f);                         \
    }                                                                  \
    acc[0] += f0; acc[1] += f1; acc[2] += f2; acc[3] += f3;            \
    acc[4] += f4; acc[5] += f5; acc[6] += f6; acc[7] += f7;            \
  }
#define GATHER(s) *(const uint4*)(h_in + ((size_t)(s) << 6) + fl)

  // ---- phase 1: gather (2 batches of 8 rows per wave; grid exact) ----
#pragma unroll
  for (int b = 0; b < 2; ++b) {
    const int r = (wave << 4) + (b << 3) + g;
    const int row = row0 + r;
    float acc[8] = {0.f, 0.f, 0.f, 0.f, 0.f, 0.f, 0.f, 0.f};
    {  // self term: all 64 lanes load (8 full rows per instruction)
      uint4 u = GATHER(row);
      ACC8(u);
    }
    const int e1 = rowptr[row + 1];
    int e = rowptr[row];
    for (; e + 7 < e1; e += 8) {
      int s0 = colidx[e];
      int s1 = colidx[e + 1];
      int s2 = colidx[e + 2];
      int s3 = colidx[e + 3];
      int s4 = colidx[e + 4];
      int s5 = colidx[e + 5];
      int s6 = colidx[e + 6];
      int s7 = colidx[e + 7];
      uint4 u0 = GATHER(s0);
      uint4 u1 = GATHER(s1);
      uint4 u2 = GATHER(s2);
      uint4 u3 = GATHER(s3);
      uint4 u4 = GATHER(s4);
      uint4 u5 = GATHER(s5);
      uint4 u6 = GATHER(s6);
      uint4 u7 = GATHER(s7);
      PIN4(u0); ACC8(u0);
      PIN4(u1); ACC8(u1);
      PIN4(u2); ACC8(u2);
      PIN4(u3); ACC8(u3);
      PIN4(u4); ACC8(u4);
      PIN4(u5); ACC8(u5);
      PIN4(u6); ACC8(u6);
      PIN4(u7); ACC8(u7);
    }
    if (e < e1) {  // masked tail: clamped loads issued up-front, predicated acc
      const int em = e1 - 1;
      int s0 = colidx[e];
      int s1 = colidx[min(e + 1, em)];
      int s2 = colidx[min(e + 2, em)];
      int s3 = colidx[min(e + 3, em)];
      int s4 = colidx[min(e + 4, em)];
      int s5 = colidx[min(e + 5, em)];
      int s6 = colidx[min(e + 6, em)];
      int s7 = colidx[min(e + 7, em)];
      uint4 u0 = GATHER(s0);
      uint4 u1 = GATHER(s1);
      uint4 u2 = GATHER(s2);
      uint4 u3 = GATHER(s3);
      uint4 u4 = GATHER(s4);
      uint4 u5 = GATHER(s5);
      uint4 u6 = GATHER(s6);
      uint4 u7 = GATHER(s7);
      PIN4(u0); ACC8(u0);
      PIN4(u1); if (e + 1 < e1) ACC8(u1);
      PIN4(u2); if (e + 2 < e1) ACC8(u2);
      PIN4(u3); if (e + 3 < e1) ACC8(u3);
      PIN4(u4); if (e + 4 < e1) ACC8(u4);
      PIN4(u5); if (e + 5 < e1) ACC8(u5);
      PIN4(u6); if (e + 6 < e1) ACC8(u6);
      PIN4(u7); if (e + 7 < e1) ACC8(u7);
    }
    *(float4*)&sT[r][fl] = make_float4(acc[0], acc[1], acc[2], acc[3]);
    *(float4*)&sT[r][fl + 4] = make_float4(acc[4], acc[5], acc[6], acc[7]);
  }
#undef GATHER
#undef ACC8
  __syncthreads();

  const int tc = tid & 15, tr = tid >> 4;  // cols 4*tc.., rows 4*tr.. (tr 0..7)

  // ---- GEMM1: h1 = relu(t @ w1 + b1), regs, write back to sT ----
  float hreg[4][4];
  {
    float acc[4][4];
#pragma unroll
    for (int i = 0; i < 4; ++i)
#pragma unroll
      for (int j = 0; j < 4; ++j) acc[i][j] = 0.f;
#pragma unroll 8
    for (int k = 0; k < 64; ++k) {
      const float4 b = ld4(&w1[(k << 6) + (tc << 2)]);
#pragma unroll
      for (int i = 0; i < 4; ++i) {
        const float a = sT[(tr << 2) + i][k];
        acc[i][0] = fmaf(a, b.x, acc[i][0]);
        acc[i][1] = fmaf(a, b.y, acc[i][1]);
        acc[i][2] = fmaf(a, b.z, acc[i][2]);
        acc[i][3] = fmaf(a, b.w, acc[i][3]);
      }
    }
    const float4 bb = ld4(&b1[tc << 2]);
#pragma unroll
    for (int i = 0; i < 4; ++i) {
      hreg[i][0] = fmaxf(acc[i][0] + bb.x, 0.f);
      hreg[i][1] = fmaxf(acc[i][1] + bb.y, 0.f);
      hreg[i][2] = fmaxf(acc[i][2] + bb.z, 0.f);
      hreg[i][3] = fmaxf(acc[i][3] + bb.w, 0.f);
    }
  }
  __syncthreads();
#pragma unroll
  for (int i = 0; i < 4; ++i)
    *(float4*)&sT[(tr << 2) + i][tc << 2] = *(float4*)&hreg[i][0];
  __syncthreads();

  // ---- GEMM2: h2 = h1 @ w2 + b2 -> global (+ BN stats) ----
  {
    float acc[4][4];
#pragma unroll
    for (int i = 0; i < 4; ++i)
#pragma unroll
      for (int j = 0; j < 4; ++j) acc[i][j] = 0.f;
#pragma unroll 8
    for (int k = 0; k < 64; ++k) {
      const float4 b = ld4(&w2[(k << 6) + (tc << 2)]);
#pragma unroll
      for (int i = 0; i < 4; ++i) {
        const float a = sT[(tr << 2) + i][k];
        acc[i][0] = fmaf(a, b.x, acc[i][0]);
        acc[i][1] = fmaf(a, b.y, acc[i][1]);
        acc[i][2] = fmaf(a, b.z, acc[i][2]);
        acc[i][3] = fmaf(a, b.w, acc[i][3]);
      }
    }
    const float4 bb = ld4(&b2[tc << 2]);
    float p[4] = {0.f, 0.f, 0.f, 0.f}, q[4] = {0.f, 0.f, 0.f, 0.f};
#pragma unroll
    for (int i = 0; i < 4; ++i) {
      const int row = row0 + (tr << 2) + i;
      float4 o;
      o.x = acc[i][0] + bb.x;
      o.y = acc[i][1] + bb.y;
      o.z = acc[i][2] + bb.z;
      o.w = acc[i][3] + bb.w;
      if (OUT_BF) {
        uintx2 o2;
        o2.x = f2bf(o.x) | (f2bf(o.y) << 16);
        o2.y = f2bf(o.z) | (f2bf(o.w) << 16);
        __builtin_nontemporal_store(o2, (uintx2*)(h_out_bf + ((size_t)row << 6) + (tc << 2)));
      } else {
        floatx4 o4;
        o4.x = o.x; o4.y = o.y; o4.z = o.z; o4.w = o.w;
        __builtin_nontemporal_store(o4, (floatx4*)&h_out_f[row * 64 + (tc << 2)]);
      }
      if (EMIT_STATS) {
        p[0] += o.x; q[0] += o.x * o.x;
        p[1] += o.y; q[1] += o.y * o.y;
        p[2] += o.z; q[2] += o.z * o.z;
        p[3] += o.w; q[3] += o.w * o.w;
      }
    }
    if (EMIT_STATS) {
#pragma unroll
      for (int j = 0; j < 4; ++j) {
        atomicAdd(&sSum[(tc << 2) + j], p[j]);
        atomicAdd(&sSq[(tc << 2) + j], q[j]);
      }
      __syncthreads();
      if (tid < 64) {
        atomicAdd(&stats[tid], sSum[tid]);
        atomicAdd(&stats[64 + tid], sSq[tid]);
      }
    }
  }
}
#undef PIN4

__global__ void k_bnfin(const float* __restrict__ stats, const float* __restrict__ gamma,
                        const float* __restrict__ beta, float* __restrict__ ss) {
  int t = threadIdx.x;
  if (t < 64) {
    const float inv_n = 1.f / (float)N_NODES;
    float mean = stats[t] * inv_n;
    float var = stats[64 + t] * inv_n - mean * mean;
    float scale = gamma[t] * rsqrtf(var + BN_EPS);
    ss[t] = scale;
    ss[64 + t] = beta[t] - mean * scale;
  }
}

// ---------------- global add pool (batch sorted) ----------------
__global__ __launch_bounds__(256) void k_pool(const float* __restrict__ h,
                                              const int* __restrict__ batch,
                                              float* __restrict__ emb) {
  const int NW = 1024;  // total waves
  const int RPW = (N_NODES + NW - 1) / NW;
  int wid = (blockIdx.x * 256 + threadIdx.x) >> 6;
  int lane = threadIdx.x & 63;
  int r0 = wid * RPW;
  if (r0 >= N_NODES) return;
  int r1 = min(r0 + RPW, N_NODES);
  float acc = 0.f;
  int curg = batch[r0];
  for (int i = r0; i < r1; ++i) {
    int g = batch[i];
    if (g != curg) {
      atomicAdd(&emb[curg * 64 + lane], acc);
      acc = 0.f;
      curg = g;
    }
    acc += h[i * 64 + lane];
  }
  atomicAdd(&emb[curg * 64 + lane], acc);
}

// ---------------- final MLP ----------------
__global__ __launch_bounds__(256) void k_mlp(const float* __restrict__ emb,
                                             const float* __restrict__ w1,
                                             const float* __restrict__ b1,
                                             const float* __restrict__ w2,
                                             const float* __restrict__ b2,
                                             float* __restrict__ out) {
  __shared__ float sp[64];
  __shared__ float smid[256];
  int g = blockIdx.x, t = threadIdx.x;
  if (t < 64) sp[t] = emb[g * 64 + t];
  __syncthreads();
  float acc = b1[t];
#pragma unroll 8
  for (int k = 0; k < 64; ++k) acc = fmaf(sp[k], w1[k * 256 + t], acc);
  smid[t] = fmaxf(acc, 0.f);
  __syncthreads();
  if (t < 128) {
    float o = b2[t];
#pragma unroll 8
    for (int k = 0; k < 256; ++k) o = fmaf(smid[k], w2[k * 128 + t], o);
    out[g * 128 + t] = o;
  }
}

extern "C" void kernel_launch(void* const* d_in, const int* in_sizes, int n_in,
                              void* d_out, int out_size, void* d_ws, size_t ws_size,
                              hipStream_t stream) {
  const float* x = (const float*)d_in[0];
  const int* edge = (const int*)d_in[1];
  const int* batch = (const int*)d_in[2];
  const float* cw1[3] = {(const float*)d_in[3], (const float*)d_in[7], (const float*)d_in[11]};
  const float* cb1[3] = {(const float*)d_in[4], (const float*)d_in[8], (const float*)d_in[12]};
  const float* cw2[3] = {(const float*)d_in[5], (const float*)d_in[9], (const float*)d_in[13]};
  const float* cb2[3] = {(const float*)d_in[6], (const float*)d_in[10], (const float*)d_in[14]};
  const float* bng[2] = {(const float*)d_in[15], (const float*)d_in[17]};
  const float* bnb[2] = {(const float*)d_in[16], (const float*)d_in[18]};
  const float* mpw1 = (const float*)d_in[19];
  const float* mpb1 = (const float*)d_in[20];
  const float* mpw2 = (const float*)d_in[21];
  const float* mpb2 = (const float*)d_in[22];

  char* ws = (char*)d_ws;
  size_t off = 0;
  auto alloc = [&](size_t bytes) {
    void* p = ws + off;
    off = (off + bytes + 255) & ~(size_t)255;
    return p;
  };
  int* rowptr = (int*)alloc((N_NODES + 1) * sizeof(int));
  int* colidx = (int*)alloc(N_EDGES * sizeof(int));
  int* bcnt = (int*)alloc(NBUCK * sizeof(int));
  int* boff = (int*)alloc(NBUCK * sizeof(int));
  int* bcur = (int*)alloc(NBUCK * sizeof(int));
  // x_bf and hA_bf contiguous (12.8 MB each); after layer 1 both are dead and
  // the combined 25.6 MB is reused as the fp32 layer-2 output hF.
  ushort* x_bf = (ushort*)alloc((size_t)N_NODES * 64 * sizeof(ushort));
  ushort* hA_bf = (ushort*)alloc((size_t)N_NODES * 64 * sizeof(ushort));
  ushort* hB_bf = (ushort*)alloc((size_t)N_NODES * 64 * sizeof(ushort));
  float* stats = (float*)alloc(2 * 128 * sizeof(float));
  float* ssbuf = (float*)alloc(2 * 128 * sizeof(float));
  float* hF = (float*)x_bf;
  // pairs (12.8 MB) aliases hB_bf: pairs is dead before layer 1 writes hB_bf.
  uint2* pairs = (uint2*)hB_bf;

  float* outp = (float*)d_out;
  float* emb = outp + N_GRAPHS * D_OUT;  // output 1 lives right after output 0

  const int* srcA = edge;
  const int* dstA = edge + N_EDGES;

  hipMemsetAsync(bcnt, 0, NBUCK * sizeof(int), stream);
  hipMemsetAsync(stats, 0, 2 * 128 * sizeof(float), stream);
  hipMemsetAsync(emb, 0, N_GRAPHS * 64 * sizeof(float), stream);

  k_cvt<<<(N_NODES * 64 / 8 + 255) / 256, 256, 0, stream>>>(x, x_bf, N_NODES * 64 / 8);
  k_hist<<<256, 256, 0, stream>>>(dstA, bcnt);
  k_bscan<<<1, 1024, 0, stream>>>(bcnt, boff, bcur);
  k_bin<<<(N_EDGES + BIN_CH - 1) / BIN_CH, 256, 0, stream>>>(srcA, dstA, bcur, pairs);
  k_bucket<<<NBUCK, 256, 0, stream>>>(pairs, boff, bcnt, rowptr, colidx);

  const int GC = N_NODES / 32;  // 3125, exact
  // layer 0: input x_bf (no BN on input), emit stats0, bf16 out
  k_conv<0, 1, 1><<<GC, 128, 0, stream>>>(x_bf, nullptr, rowptr, colidx, cw1[0], cb1[0],
                                          cw2[0], cb2[0], nullptr, hA_bf, stats);
  k_bnfin<<<1, 64, 0, stream>>>(stats, bng[0], bnb[0], ssbuf);
  // layer 1: input hA_bf with BN0+relu on the fly, emit stats1, bf16 out
  k_conv<1, 1, 1><<<GC, 128, 0, stream>>>(hA_bf, ssbuf, rowptr, colidx, cw1[1], cb1[1],
                                          cw2[1], cb2[1], nullptr, hB_bf, stats + 128);
  k_bnfin<<<1, 64, 0, stream>>>(stats + 128, bng[1], bnb[1], ssbuf + 128);
  // layer 2: input hB_bf with BN1+relu, fp32 out for pooling
  k_conv<1, 0, 0><<<GC, 128, 0, stream>>>(hB_bf, ssbuf + 128, rowptr, colidx, cw1[2],
                                          cb1[2], cw2[2], cb2[2], hF, nullptr, nullptr);

  k_pool<<<256, 256, 0, stream>>>(hF, batch, emb);
  k_mlp<<<N_GRAPHS, 256, 0, stream>>>(emb, mpw1, mpb1, mpw2, mpb2, outp);
}